// Round 17
// baseline (475.692 us; speedup 1.0000x reference)
//
#include <hip/hip_runtime.h>

#define N_NODES 100000
#define E_EDGES 300000
#define N_GRAPHS 2048

typedef float  floatx4 __attribute__((ext_vector_type(4)));
typedef short  shortx8 __attribute__((ext_vector_type(8)));

__device__ __forceinline__ float bf2f(unsigned short u) {
  return __uint_as_float(((unsigned int)u) << 16);
}
__device__ __forceinline__ unsigned short f2bf(float f) {
  unsigned int u = __float_as_uint(f);
  u += 0x7FFFu + ((u >> 16) & 1u);
  return (unsigned short)(u >> 16);
}

// async global->LDS, 16B per lane; lds base wave-uniform, dst = base+lane*16 (m104)
__device__ __forceinline__ void cp16(const void* g, void* l) {
  __builtin_amdgcn_global_load_lds(
      (const __attribute__((address_space(1))) unsigned int*)g,
      (__attribute__((address_space(3))) unsigned int*)l, 16, 0, 0);
}

// ---- prep kernel: all independent prologue work in ONE dispatch -------------
// roles by blockIdx.x:
//   [0,320)    weight transpose fp32->bf16 (4 jobs)
//   [320,361)  WfT = (We@W1_0)^T, slot40 = be@W1_0, 41..63 = 0
//   [361,490)  w2v[k] = W2_2[k,:] . wtask   (+ c2 = b2_2 . wtask)
//   [490,881)  nodedot = 0
//   [881,889)  out[g] = b_task[0]
struct PrepArgs {
  const float* W[4];       // transpose jobs
  unsigned short* Wt[4];
  int K[4];
  int N[4];
  const float* We;
  const float* be;
  const float* W1_0;
  unsigned short* WfT;
  const float* W2_2;
  const float* b2_2;
  const float* wtask;
  float* w2v;
  float* c2;
  float* nodedot;
  float* out;
  const float* b_task;
};

__global__ __launch_bounds__(256)
void prep_kernel(PrepArgs a) {
  const int blk = blockIdx.x;
  if (blk < 320) {
    // transpose: job offsets {0,64,128,192}..320
    int z, b;
    if (blk < 64)       { z = 0; b = blk; }
    else if (blk < 128) { z = 1; b = blk - 64; }
    else if (blk < 192) { z = 2; b = blk - 128; }
    else                { z = 3; b = blk - 192; }
    const int K = a.K[z], N = a.N[z];
    const int nt = N / 32;
    const int kb = (b / nt) * 32, nb = (b % nt) * 32;
    __shared__ unsigned short tile[32][33];
    const float* W = a.W[z];
    unsigned short* Wt = a.Wt[z];
    const int tx = threadIdx.x & 31, ty = threadIdx.x >> 5;
    for (int r = ty; r < 32; r += 8)
      tile[r][tx] = f2bf(W[(size_t)(kb + r) * N + nb + tx]);
    __syncthreads();
    for (int r = ty; r < 32; r += 8)
      Wt[(size_t)(nb + r) * K + kb + tx] = tile[tx][r];
  } else if (blk < 361) {
    const int k = blk - 320;  // 0..40
    const int n = threadIdx.x;
    if (k < 40) {
      float s = 0.f;
      for (int j = 0; j < 128; j++) s = fmaf(a.We[k * 128 + j], a.W1_0[(size_t)j * 256 + n], s);
      a.WfT[n * 64 + k] = f2bf(s);
    } else {
      float s = 0.f;
      for (int j = 0; j < 128; j++) s = fmaf(a.be[j], a.W1_0[(size_t)j * 256 + n], s);
      a.WfT[n * 64 + 40] = f2bf(s);
      for (int kk = 41; kk < 64; kk++) a.WfT[n * 64 + kk] = 0;
    }
  } else if (blk < 490) {
    const int p = blk - 361;  // 0..128
    const int lane = threadIdx.x & 63;
    const int wave = threadIdx.x >> 6;
    if (p < 128) {
      const int k = p * 4 + wave;
      const float* row = a.W2_2 + (size_t)k * 512 + lane * 8;
      float4 a0 = *(const float4*)(row);
      float4 a1 = *(const float4*)(row + 4);
      float4 w0 = *(const float4*)(a.wtask + lane * 8);
      float4 w1 = *(const float4*)(a.wtask + lane * 8 + 4);
      float s = a0.x * w0.x + a0.y * w0.y + a0.z * w0.z + a0.w * w0.w +
                a1.x * w1.x + a1.y * w1.y + a1.z * w1.z + a1.w * w1.w;
#pragma unroll
      for (int off = 32; off > 0; off >>= 1) s += __shfl_down(s, off);
      if (lane == 0) a.w2v[k] = s;
    } else if (wave == 0) {
      float4 a0 = *(const float4*)(a.b2_2 + lane * 8);
      float4 a1 = *(const float4*)(a.b2_2 + lane * 8 + 4);
      float4 w0 = *(const float4*)(a.wtask + lane * 8);
      float4 w1 = *(const float4*)(a.wtask + lane * 8 + 4);
      float s = a0.x * w0.x + a0.y * w0.y + a0.z * w0.z + a0.w * w0.w +
                a1.x * w1.x + a1.y * w1.y + a1.z * w1.z + a1.w * w1.w;
#pragma unroll
      for (int off = 32; off > 0; off >>= 1) s += __shfl_down(s, off);
      if (lane == 0) *a.c2 = s;
    }
  } else if (blk < 881) {
    int i = (blk - 490) * 256 + threadIdx.x;
    if (i < N_NODES) a.nodedot[i] = 0.f;
  } else {
    int g = (blk - 881) * 256 + threadIdx.x;
    if (g < N_GRAPHS) a.out[g] = a.b_task[0];
  }
}

// ---------------- CSR build: zero, histogram, scan, fill ---------------------
__global__ __launch_bounds__(256)
void zero_kernel(int* __restrict__ p, int n) {
  int i = blockIdx.x * 256 + threadIdx.x;
  if (i < n) p[i] = 0;
}

__global__ __launch_bounds__(256)
void hist_kernel(const int* __restrict__ ei, int* __restrict__ deg) {
  int e = blockIdx.x * 256 + threadIdx.x;
  if (e < E_EDGES) atomicAdd(&deg[ei[E_EDGES + e]], 1);
}

__global__ __launch_bounds__(256)
void scan_blk_kernel(const int* __restrict__ in, int* __restrict__ out,
                     int* __restrict__ blk_sums, int n_in, int n_out) {
  __shared__ int sm[256];
  const int t = threadIdx.x;
  const int base = blockIdx.x * 1024 + t * 4;
  int d0 = (base + 0 < n_in) ? in[base + 0] : 0;
  int d1 = (base + 1 < n_in) ? in[base + 1] : 0;
  int d2 = (base + 2 < n_in) ? in[base + 2] : 0;
  int d3 = (base + 3 < n_in) ? in[base + 3] : 0;
  int s = d0 + d1 + d2 + d3;
  sm[t] = s;
  __syncthreads();
  for (int off = 1; off < 256; off <<= 1) {
    int v = (t >= off) ? sm[t - off] : 0;
    __syncthreads();
    sm[t] += v;
    __syncthreads();
  }
  int excl = sm[t] - s;
  if (base + 0 < n_out) out[base + 0] = excl;
  if (base + 1 < n_out) out[base + 1] = excl + d0;
  if (base + 2 < n_out) out[base + 2] = excl + d0 + d1;
  if (base + 3 < n_out) out[base + 3] = excl + d0 + d1 + d2;
  if (t == 255 && blk_sums) blk_sums[blockIdx.x] = sm[255];
}

__global__ __launch_bounds__(256)
void scan_fix_kernel(int* __restrict__ row_ptr, const int* __restrict__ blk_off,
                     int* __restrict__ cursor) {
  int i = blockIdx.x * 256 + threadIdx.x;
  if (i <= N_NODES) {
    int v = row_ptr[i] + blk_off[i >> 10];
    row_ptr[i] = v;
    if (i < N_NODES) cursor[i] = v;
  }
}

__global__ __launch_bounds__(256)
void fill_kernel(const int* __restrict__ ei, int* __restrict__ cursor,
                 int* __restrict__ csr_src) {
  int e = blockIdx.x * 256 + threadIdx.x;
  if (e < E_EDGES) {
    int d = ei[E_EDGES + e];
    int slot = atomicAdd(&cursor[d], 1);
    csr_src[slot] = ei[e];
  }
}

// ---- gatherx: G[n,64] = bf16([(1+eps)X_n + sum X_src | f_n | 0...]) ---------
// edge loop unrolled x4 (R16)
__global__ __launch_bounds__(256)
void gatherx_kernel(const float* __restrict__ X, unsigned short* __restrict__ G,
                    const int* __restrict__ row_ptr, const int* __restrict__ csr,
                    const float* __restrict__ eps) {
  const int node = blockIdx.x * 4 + (threadIdx.x >> 6);
  const int lane = threadIdx.x & 63;
  const float sc = 1.0f + eps[0];
  const int e0 = row_ptr[node];
  const int e1 = row_ptr[node + 1];
  float acc = 0.f;
  if (lane < 40) {
    acc = sc * X[(size_t)node * 40 + lane];
    int e = e0;
    for (; e + 4 <= e1; e += 4) {
      int s0 = csr[e], s1 = csr[e + 1], s2 = csr[e + 2], s3 = csr[e + 3];
      float a0 = X[(size_t)s0 * 40 + lane];
      float a1 = X[(size_t)s1 * 40 + lane];
      float a2 = X[(size_t)s2 * 40 + lane];
      float a3 = X[(size_t)s3 * 40 + lane];
      acc += (a0 + a1) + (a2 + a3);
    }
    for (; e < e1; e++)
      acc += X[(size_t)csr[e] * 40 + lane];
  } else if (lane == 40) {
    acc = sc + (float)(e1 - e0);
  }
  G[(size_t)node * 64 + lane] = f2bf(acc);
}

// ------- gather (D=256): Z[d] = bf16((1+eps)*H[d] + sum H[src]) --------------
// TWO waves per node: each wave owns a 128-feature half-row (4B/lane) and
// walks the edge list independently -> 200k independent dependent-load chains
// (vs 100k) with no max(degA,degB) coupling (R15's mistake). csr loads are
// duplicated across the node's two waves but L1-resident. Unroll x4.
__global__ __launch_bounds__(256)
void gather_kernel(const unsigned short* __restrict__ H, unsigned short* __restrict__ Z,
                   const int* __restrict__ row_ptr, const int* __restrict__ csr,
                   const float* __restrict__ eps, int l) {
  const int w = blockIdx.x * 4 + (threadIdx.x >> 6);
  const int node = w >> 1;
  const int half = w & 1;
  const int lane = threadIdx.x & 63;
  const int col = half * 128 + lane * 2;  // bf16 index within row
  const float sc = 1.0f + eps[l];
  unsigned int hv = *(const unsigned int*)(H + (size_t)node * 256 + col);
  float acc0 = sc * bf2f((unsigned short)(hv & 0xFFFF));
  float acc1 = sc * bf2f((unsigned short)(hv >> 16));
  const int e0 = row_ptr[node];
  const int e1 = row_ptr[node + 1];
  int e = e0;
  for (; e + 4 <= e1; e += 4) {
    int s0 = csr[e], s1 = csr[e + 1], s2 = csr[e + 2], s3 = csr[e + 3];
    unsigned int a = *(const unsigned int*)(H + (size_t)s0 * 256 + col);
    unsigned int b = *(const unsigned int*)(H + (size_t)s1 * 256 + col);
    unsigned int c = *(const unsigned int*)(H + (size_t)s2 * 256 + col);
    unsigned int d = *(const unsigned int*)(H + (size_t)s3 * 256 + col);
    acc0 += (bf2f((unsigned short)(a & 0xFFFF)) + bf2f((unsigned short)(b & 0xFFFF))) +
            (bf2f((unsigned short)(c & 0xFFFF)) + bf2f((unsigned short)(d & 0xFFFF)));
    acc1 += (bf2f((unsigned short)(a >> 16)) + bf2f((unsigned short)(b >> 16))) +
            (bf2f((unsigned short)(c >> 16)) + bf2f((unsigned short)(d >> 16)));
  }
  for (; e < e1; e++) {
    unsigned int a = *(const unsigned int*)(H + (size_t)csr[e] * 256 + col);
    acc0 += bf2f((unsigned short)(a & 0xFFFF));
    acc1 += bf2f((unsigned short)(a >> 16));
  }
  unsigned short z[2] = {f2bf(acc0), f2bf(acc1)};
  *(unsigned int*)(Z + (size_t)node * 256 + col) = *(unsigned int*)z;
}

// ---- GEMM (R16): act(A @ Bt^T + bias), 128x128, BK=64, launch_bounds(256,4) -
// XOR swizzle (0 conflicts) + LDS-staged epilogue + XCD block swizzle +
// reg cap 128/wave -> 4 blocks/CU (VGPR 64, occupancy 32%, no spill).
// MODE 0: C = bf16(relu). MODE 3: nodedot += sum relu(.)*w2v.
template <int K, int NXL, int MODE>
__global__ __launch_bounds__(256, 4)
void gemm_kernel(const unsigned short* __restrict__ A,
                 const unsigned short* __restrict__ Bt,
                 const float* __restrict__ bias, unsigned short* __restrict__ C,
                 const float* __restrict__ w2v, float* __restrict__ nodedot,
                 int M, int N) {
  const int g = blockIdx.x;
  const int mblk = ((g >> (3 + NXL)) << 3) | (g & 7);
  const int nblk = (g >> 3) & ((1 << NXL) - 1);
  const int m0 = mblk * 128;
  const int n0 = nblk * 128;
  if (m0 >= M) return;

  __shared__ unsigned short smem[2 * 128 * 64];  // 32 KB: As+Bs, reused as C-tile
  unsigned short* As = smem;
  unsigned short* Bs = smem + 128 * 64;
  const int tid = threadIdx.x;
  const int lane = tid & 63;
  const int wave = tid >> 6;
  const int wm = (wave & 1) * 64;
  const int wn = (wave >> 1) * 64;
  const int fr = lane & 15;
  const int fq = lane >> 4;

  floatx4 acc[4][4];
#pragma unroll
  for (int i = 0; i < 4; i++)
#pragma unroll
    for (int j = 0; j < 4; j++) acc[i][j] = (floatx4){0.f, 0.f, 0.f, 0.f};

  const unsigned short* gA[4];
  const unsigned short* gB[4];
  unsigned short* lA[4];
  unsigned short* lB[4];
#pragma unroll
  for (int p = 0; p < 4; p++) {
    int c = p * 256 + wave * 64 + lane;
    int row = c >> 3;
    int q = (c & 7) ^ (row & 7);
    int grA = m0 + row;
    if (grA >= M) grA = M - 1;
    gA[p] = A + (size_t)grA * K + q * 8;
    gB[p] = Bt + (size_t)(n0 + row) * K + q * 8;
    lA[p] = &As[(p * 256 + wave * 64) * 8];
    lB[p] = &Bs[(p * 256 + wave * 64) * 8];
  }

  for (int k0 = 0; k0 < K; k0 += 64) {
#pragma unroll
    for (int p = 0; p < 4; p++) cp16(gA[p] + k0, lA[p]);
#pragma unroll
    for (int p = 0; p < 4; p++) cp16(gB[p] + k0, lB[p]);
    __syncthreads();
#pragma unroll
    for (int s0 = 0; s0 < 2; s0++) {
      shortx8 af[4], bf[4];
#pragma unroll
      for (int i = 0; i < 4; i++)
        af[i] = *(const shortx8*)&As[(wm + i * 16 + fr) * 64 +
                                     (((s0 * 4 + fq) ^ (fr & 7)) * 8)];
#pragma unroll
      for (int j = 0; j < 4; j++)
        bf[j] = *(const shortx8*)&Bs[(wn + j * 16 + fr) * 64 +
                                     (((s0 * 4 + fq) ^ (fr & 7)) * 8)];
#pragma unroll
      for (int i = 0; i < 4; i++)
#pragma unroll
        for (int j = 0; j < 4; j++)
          acc[i][j] = __builtin_amdgcn_mfma_f32_16x16x32_bf16(af[i], bf[j], acc[i][j], 0, 0, 0);
    }
    __syncthreads();
  }

  if (MODE == 3) {
    float wv[4], bj[4];
#pragma unroll
    for (int j = 0; j < 4; j++) {
      int col = n0 + wn + j * 16 + fr;
      wv[j] = w2v[col];
      bj[j] = bias[col];
    }
#pragma unroll
    for (int i = 0; i < 4; i++) {
#pragma unroll
      for (int r = 0; r < 4; r++) {
        float p = 0.f;
#pragma unroll
        for (int j = 0; j < 4; j++) p += fmaxf(acc[i][j][r] + bj[j], 0.f) * wv[j];
#pragma unroll
        for (int off = 1; off < 16; off <<= 1) p += __shfl_xor(p, off);
        if (fr == 0) {
          int row = m0 + wm + i * 16 + fq * 4 + r;
          if (row < M) unsafeAtomicAdd(&nodedot[row], p);
        }
      }
    }
  } else {
    unsigned short* Cs = smem;
#pragma unroll
    for (int j = 0; j < 4; j++) {
      int col = wn + j * 16 + fr;
      float bj = bias[n0 + col];
#pragma unroll
      for (int i = 0; i < 4; i++) {
#pragma unroll
        for (int r = 0; r < 4; r++) {
          int row = wm + i * 16 + fq * 4 + r;
          Cs[row * 128 + col] = f2bf(fmaxf(acc[i][j][r] + bj, 0.f));
        }
      }
    }
    __syncthreads();
    const int rcol = (tid & 15) * 8;
#pragma unroll
    for (int p = 0; p < 8; p++) {
      int row = p * 16 + (tid >> 4);
      int grow = m0 + row;
      if (grow < M) {
        uint4 v = *(const uint4*)&Cs[row * 128 + rcol];
        *(uint4*)&C[(size_t)grow * N + n0 + rcol] = v;
      }
    }
  }
}

// ---------------- readout ----------------------------------------------------
// pool adds c2 (the W2_2/b2_2-fold constant) per node: sum(dot_i + c2) over g
__global__ __launch_bounds__(256)
void pool_kernel(const float* __restrict__ nodedot, const int* __restrict__ batch,
                 float* __restrict__ out, const float* __restrict__ c2p) {
  int t = blockIdx.x * 256 + threadIdx.x;
  int i0 = t * 64;
  if (i0 >= N_NODES) return;
  int i1 = i0 + 64;
  if (i1 > N_NODES) i1 = N_NODES;
  const float c2 = *c2p;
  int g = batch[i0];
  float s = 0.f;
  for (int i = i0; i < i1; i++) {
    int gi = batch[i];
    if (gi != g) { unsafeAtomicAdd(&out[g], s); g = gi; s = 0.f; }
    s += nodedot[i] + c2;
  }
  unsafeAtomicAdd(&out[g], s);
}

extern "C" void kernel_launch(void* const* d_in, const int* in_sizes, int n_in,
                              void* d_out, int out_size, void* d_ws, size_t ws_size,
                              hipStream_t stream) {
  const float* x       = (const float*)d_in[0];
  const int*   ei      = (const int*)d_in[1];
  const int*   batch   = (const int*)d_in[2];
  const float* W_embed = (const float*)d_in[3];
  const float* b_embed = (const float*)d_in[4];
  const float* eps     = (const float*)d_in[5];
  const float* W1[3] = {(const float*)d_in[6],  (const float*)d_in[10], (const float*)d_in[14]};
  const float* B1[3] = {(const float*)d_in[7],  (const float*)d_in[11], (const float*)d_in[15]};
  const float* W2[3] = {(const float*)d_in[8],  (const float*)d_in[12], (const float*)d_in[16]};
  const float* B2[3] = {(const float*)d_in[9],  (const float*)d_in[13], (const float*)d_in[17]};
  const float* W_task = (const float*)d_in[18];
  const float* b_task = (const float*)d_in[19];
  float* out = (float*)d_out;

  const size_t OFF_RB  = 51200000;
  const size_t OFF_RZ  = 102400000;
  const size_t OFF_AUX = 153600000;
  if (ws_size < OFF_AUX + 4000000) return;
  unsigned short* RH = (unsigned short*)d_ws;
  unsigned short* RB = (unsigned short*)((char*)d_ws + OFF_RB);
  unsigned short* RZ = (unsigned short*)((char*)d_ws + OFF_RZ);
  char* aux = (char*)d_ws + OFF_AUX;
  int* row_ptr  = (int*)(aux);               // 100001 ints
  int* cursor   = (int*)(aux + 400016);      // 100000 ints (also deg histogram)
  int* csr_src  = (int*)(aux + 800016);      // 300000 ints
  int* blk_sums = (int*)(aux + 2000016);     // 98 ints
  int* blk_off  = (int*)(aux + 2000416);     // 98 ints
  float* nodedot = (float*)(aux + 2000816);  // 100000 floats
  unsigned short* WT = (unsigned short*)(aux + 2400832);  // 360448 bf16
  float* w2v = (float*)(aux + 3200832);      // 512 floats
  float* c2  = (float*)(aux + 3202880);      // 1 float
  unsigned short* WfT    = WT;
  unsigned short* Wt2_0  = WT + 32768;
  unsigned short* Wt1_1  = WT + 98304;
  unsigned short* Wt2_1  = WT + 163840;
  unsigned short* Wt1_2  = WT + 229376;

  // ---- prep: all independent prologue work (1 dispatch) ----
  PrepArgs pa;
  pa.W[0] = W2[0]; pa.Wt[0] = Wt2_0; pa.K[0] = 256; pa.N[0] = 256;
  pa.W[1] = W1[1]; pa.Wt[1] = Wt1_1; pa.K[1] = 256; pa.N[1] = 256;
  pa.W[2] = W2[1]; pa.Wt[2] = Wt2_1; pa.K[2] = 256; pa.N[2] = 256;
  pa.W[3] = W1[2]; pa.Wt[3] = Wt1_2; pa.K[3] = 256; pa.N[3] = 512;
  pa.We = W_embed; pa.be = b_embed; pa.W1_0 = W1[0]; pa.WfT = WfT;
  pa.W2_2 = W2[2]; pa.b2_2 = B2[2]; pa.wtask = W_task; pa.w2v = w2v; pa.c2 = c2;
  pa.nodedot = nodedot; pa.out = out; pa.b_task = b_task;
  prep_kernel<<<889, 256, 0, stream>>>(pa);

  // ---- CSR build ----
  zero_kernel<<<(N_NODES + 255) / 256, 256, 0, stream>>>(cursor, N_NODES);
  hist_kernel<<<(E_EDGES + 255) / 256, 256, 0, stream>>>(ei, cursor);
  scan_blk_kernel<<<98, 256, 0, stream>>>(cursor, row_ptr, blk_sums, N_NODES, N_NODES + 1);
  scan_blk_kernel<<<1, 256, 0, stream>>>(blk_sums, blk_off, nullptr, 98, 98);
  scan_fix_kernel<<<(N_NODES + 256) / 256, 256, 0, stream>>>(row_ptr, blk_off, cursor);
  fill_kernel<<<(E_EDGES + 255) / 256, 256, 0, stream>>>(ei, cursor, csr_src);

  const int MB = (N_NODES + 127) / 128;       // 782
  const int MB8 = ((MB + 7) / 8) * 8;         // 784 (padded; tail blocks exit)

  // ---- layer 0 (folded): G = gather(X)+deg-slot -> T0 = relu(G@WfT^T + b1) --
  gatherx_kernel<<<N_NODES / 4, 256, 0, stream>>>(x, RZ, row_ptr, csr_src, eps);
  gemm_kernel<64, 1, 0><<<2 * MB8, 256, 0, stream>>>(RZ, WfT, B1[0], RB, nullptr, nullptr, N_NODES, 256);
  gemm_kernel<256, 1, 0><<<2 * MB8, 256, 0, stream>>>(RB, Wt2_0, B2[0], RH, nullptr, nullptr, N_NODES, 256);

  // ---- layer 1 ----
  gather_kernel<<<N_NODES / 2, 256, 0, stream>>>(RH, RZ, row_ptr, csr_src, eps, 1);
  gemm_kernel<256, 1, 0><<<2 * MB8, 256, 0, stream>>>(RZ, Wt1_1, B1[1], RB, nullptr, nullptr, N_NODES, 256);
  gemm_kernel<256, 1, 0><<<2 * MB8, 256, 0, stream>>>(RB, Wt2_1, B2[1], RH, nullptr, nullptr, N_NODES, 256);

  // ---- layer 2: gather, then MODE-3 GEMM (task-dot fused) ----
  gather_kernel<<<N_NODES / 2, 256, 0, stream>>>(RH, RZ, row_ptr, csr_src, eps, 2);
  gemm_kernel<256, 2, 3><<<4 * MB8, 256, 0, stream>>>(RZ, Wt1_2, B1[2], nullptr, w2v, nodedot, N_NODES, 512);

  // ---- out[g] = b_task + sum_i (nodedot_i + c2) ----
  pool_kernel<<<((N_NODES + 63) / 64 + 255) / 256, 256, 0, stream>>>(nodedot, batch, out, c2);
}

// Round 18
// 442.145 us; speedup vs baseline: 1.0759x; 1.0759x over previous
//
#include <hip/hip_runtime.h>

#define N_NODES 100000
#define E_EDGES 300000
#define N_GRAPHS 2048

typedef float  floatx4 __attribute__((ext_vector_type(4)));
typedef short  shortx8 __attribute__((ext_vector_type(8)));

__device__ __forceinline__ float bf2f(unsigned short u) {
  return __uint_as_float(((unsigned int)u) << 16);
}
__device__ __forceinline__ unsigned short f2bf(float f) {
  unsigned int u = __float_as_uint(f);
  u += 0x7FFFu + ((u >> 16) & 1u);
  return (unsigned short)(u >> 16);
}

// async global->LDS, 16B per lane; lds base wave-uniform, dst = base+lane*16 (m104)
__device__ __forceinline__ void cp16(const void* g, void* l) {
  __builtin_amdgcn_global_load_lds(
      (const __attribute__((address_space(1))) unsigned int*)g,
      (__attribute__((address_space(3))) unsigned int*)l, 16, 0, 0);
}

// ---- prep kernel: all independent prologue work in ONE dispatch -------------
struct PrepArgs {
  const float* W[4];
  unsigned short* Wt[4];
  int K[4];
  int N[4];
  const float* We;
  const float* be;
  const float* W1_0;
  unsigned short* WfT;
  const float* W2_2;
  const float* b2_2;
  const float* wtask;
  float* w2v;
  float* c2;
  float* nodedot;
  float* out;
  const float* b_task;
};

__global__ __launch_bounds__(256)
void prep_kernel(PrepArgs a) {
  const int blk = blockIdx.x;
  if (blk < 320) {
    int z, b;
    if (blk < 64)       { z = 0; b = blk; }
    else if (blk < 128) { z = 1; b = blk - 64; }
    else if (blk < 192) { z = 2; b = blk - 128; }
    else                { z = 3; b = blk - 192; }
    const int K = a.K[z], N = a.N[z];
    const int nt = N / 32;
    const int kb = (b / nt) * 32, nb = (b % nt) * 32;
    __shared__ unsigned short tile[32][33];
    const float* W = a.W[z];
    unsigned short* Wt = a.Wt[z];
    const int tx = threadIdx.x & 31, ty = threadIdx.x >> 5;
    for (int r = ty; r < 32; r += 8)
      tile[r][tx] = f2bf(W[(size_t)(kb + r) * N + nb + tx]);
    __syncthreads();
    for (int r = ty; r < 32; r += 8)
      Wt[(size_t)(nb + r) * K + kb + tx] = tile[tx][r];
  } else if (blk < 361) {
    const int k = blk - 320;  // 0..40
    const int n = threadIdx.x;
    if (k < 40) {
      float s = 0.f;
      for (int j = 0; j < 128; j++) s = fmaf(a.We[k * 128 + j], a.W1_0[(size_t)j * 256 + n], s);
      a.WfT[n * 64 + k] = f2bf(s);
    } else {
      float s = 0.f;
      for (int j = 0; j < 128; j++) s = fmaf(a.be[j], a.W1_0[(size_t)j * 256 + n], s);
      a.WfT[n * 64 + 40] = f2bf(s);
      for (int kk = 41; kk < 64; kk++) a.WfT[n * 64 + kk] = 0;
    }
  } else if (blk < 490) {
    const int p = blk - 361;  // 0..128
    const int lane = threadIdx.x & 63;
    const int wave = threadIdx.x >> 6;
    if (p < 128) {
      const int k = p * 4 + wave;
      const float* row = a.W2_2 + (size_t)k * 512 + lane * 8;
      float4 a0 = *(const float4*)(row);
      float4 a1 = *(const float4*)(row + 4);
      float4 w0 = *(const float4*)(a.wtask + lane * 8);
      float4 w1 = *(const float4*)(a.wtask + lane * 8 + 4);
      float s = a0.x * w0.x + a0.y * w0.y + a0.z * w0.z + a0.w * w0.w +
                a1.x * w1.x + a1.y * w1.y + a1.z * w1.z + a1.w * w1.w;
#pragma unroll
      for (int off = 32; off > 0; off >>= 1) s += __shfl_down(s, off);
      if (lane == 0) a.w2v[k] = s;
    } else if (wave == 0) {
      float4 a0 = *(const float4*)(a.b2_2 + lane * 8);
      float4 a1 = *(const float4*)(a.b2_2 + lane * 8 + 4);
      float4 w0 = *(const float4*)(a.wtask + lane * 8);
      float4 w1 = *(const float4*)(a.wtask + lane * 8 + 4);
      float s = a0.x * w0.x + a0.y * w0.y + a0.z * w0.z + a0.w * w0.w +
                a1.x * w1.x + a1.y * w1.y + a1.z * w1.z + a1.w * w1.w;
#pragma unroll
      for (int off = 32; off > 0; off >>= 1) s += __shfl_down(s, off);
      if (lane == 0) *a.c2 = s;
    }
  } else if (blk < 881) {
    int i = (blk - 490) * 256 + threadIdx.x;
    if (i < N_NODES) a.nodedot[i] = 0.f;
  } else {
    int g = (blk - 881) * 256 + threadIdx.x;
    if (g < N_GRAPHS) a.out[g] = a.b_task[0];
  }
}

// ---------------- CSR build: zero, histogram, scan, fill ---------------------
__global__ __launch_bounds__(256)
void zero_kernel(int* __restrict__ p, int n) {
  int i = blockIdx.x * 256 + threadIdx.x;
  if (i < n) p[i] = 0;
}

__global__ __launch_bounds__(256)
void hist_kernel(const int* __restrict__ ei, int* __restrict__ deg) {
  int e = blockIdx.x * 256 + threadIdx.x;
  if (e < E_EDGES) atomicAdd(&deg[ei[E_EDGES + e]], 1);
}

__global__ __launch_bounds__(256)
void scan_blk_kernel(const int* __restrict__ in, int* __restrict__ out,
                     int* __restrict__ blk_sums, int n_in, int n_out) {
  __shared__ int sm[256];
  const int t = threadIdx.x;
  const int base = blockIdx.x * 1024 + t * 4;
  int d0 = (base + 0 < n_in) ? in[base + 0] : 0;
  int d1 = (base + 1 < n_in) ? in[base + 1] : 0;
  int d2 = (base + 2 < n_in) ? in[base + 2] : 0;
  int d3 = (base + 3 < n_in) ? in[base + 3] : 0;
  int s = d0 + d1 + d2 + d3;
  sm[t] = s;
  __syncthreads();
  for (int off = 1; off < 256; off <<= 1) {
    int v = (t >= off) ? sm[t - off] : 0;
    __syncthreads();
    sm[t] += v;
    __syncthreads();
  }
  int excl = sm[t] - s;
  if (base + 0 < n_out) out[base + 0] = excl;
  if (base + 1 < n_out) out[base + 1] = excl + d0;
  if (base + 2 < n_out) out[base + 2] = excl + d0 + d1;
  if (base + 3 < n_out) out[base + 3] = excl + d0 + d1 + d2;
  if (t == 255 && blk_sums) blk_sums[blockIdx.x] = sm[255];
}

__global__ __launch_bounds__(256)
void scan_fix_kernel(int* __restrict__ row_ptr, const int* __restrict__ blk_off,
                     int* __restrict__ cursor) {
  int i = blockIdx.x * 256 + threadIdx.x;
  if (i <= N_NODES) {
    int v = row_ptr[i] + blk_off[i >> 10];
    row_ptr[i] = v;
    if (i < N_NODES) cursor[i] = v;
  }
}

__global__ __launch_bounds__(256)
void fill_kernel(const int* __restrict__ ei, int* __restrict__ cursor,
                 int* __restrict__ csr_src) {
  int e = blockIdx.x * 256 + threadIdx.x;
  if (e < E_EDGES) {
    int d = ei[E_EDGES + e];
    int slot = atomicAdd(&cursor[d], 1);
    csr_src[slot] = ei[e];
  }
}

// ---- gatherx: G[n,64] = bf16([(1+eps)X_n + sum X_src | f_n | 0...]) ---------
// edge loop unrolled x4 (R16 — left the top-5 after unrolling)
__global__ __launch_bounds__(256)
void gatherx_kernel(const float* __restrict__ X, unsigned short* __restrict__ G,
                    const int* __restrict__ row_ptr, const int* __restrict__ csr,
                    const float* __restrict__ eps) {
  const int node = blockIdx.x * 4 + (threadIdx.x >> 6);
  const int lane = threadIdx.x & 63;
  const float sc = 1.0f + eps[0];
  const int e0 = row_ptr[node];
  const int e1 = row_ptr[node + 1];
  float acc = 0.f;
  if (lane < 40) {
    acc = sc * X[(size_t)node * 40 + lane];
    int e = e0;
    for (; e + 4 <= e1; e += 4) {
      int s0 = csr[e], s1 = csr[e + 1], s2 = csr[e + 2], s3 = csr[e + 3];
      float a0 = X[(size_t)s0 * 40 + lane];
      float a1 = X[(size_t)s1 * 40 + lane];
      float a2 = X[(size_t)s2 * 40 + lane];
      float a3 = X[(size_t)s3 * 40 + lane];
      acc += (a0 + a1) + (a2 + a3);
    }
    for (; e < e1; e++)
      acc += X[(size_t)csr[e] * 40 + lane];
  } else if (lane == 40) {
    acc = sc + (float)(e1 - e0);
  }
  G[(size_t)node * 64 + lane] = f2bf(acc);
}

// ------- gather (D=256): Z[d] = bf16((1+eps)*H[d] + sum H[src]) --------------
// R14 exact form: ONE wave per node, uint2 (8B) loads, simple loop.
// (R15 half-wave pairing: max(deg) coupling regressed. R17 two-waves/node:
// doubled FETCH 50->99.7 MB, line-locality loss regressed. R16 unroll: no
// measurable gain. This is the best-measured variant.)
__global__ __launch_bounds__(256)
void gather_kernel(const unsigned short* __restrict__ H, unsigned short* __restrict__ Z,
                   const int* __restrict__ row_ptr, const int* __restrict__ csr,
                   const float* __restrict__ eps, int l) {
  const int node = blockIdx.x * 4 + (threadIdx.x >> 6);
  const int lane = threadIdx.x & 63;
  const float sc = 1.0f + eps[l];
  uint2 hv = *(const uint2*)(H + (size_t)node * 256 + lane * 4);
  float acc[4];
  acc[0] = sc * bf2f((unsigned short)(hv.x & 0xFFFF));
  acc[1] = sc * bf2f((unsigned short)(hv.x >> 16));
  acc[2] = sc * bf2f((unsigned short)(hv.y & 0xFFFF));
  acc[3] = sc * bf2f((unsigned short)(hv.y >> 16));
  const int e0 = row_ptr[node];
  const int e1 = row_ptr[node + 1];
  int e = e0;
  for (; e + 2 <= e1; e += 2) {
    int s0 = csr[e], s1 = csr[e + 1];
    uint2 a = *(const uint2*)(H + (size_t)s0 * 256 + lane * 4);
    uint2 b = *(const uint2*)(H + (size_t)s1 * 256 + lane * 4);
    acc[0] += bf2f((unsigned short)(a.x & 0xFFFF)) + bf2f((unsigned short)(b.x & 0xFFFF));
    acc[1] += bf2f((unsigned short)(a.x >> 16))    + bf2f((unsigned short)(b.x >> 16));
    acc[2] += bf2f((unsigned short)(a.y & 0xFFFF)) + bf2f((unsigned short)(b.y & 0xFFFF));
    acc[3] += bf2f((unsigned short)(a.y >> 16))    + bf2f((unsigned short)(b.y >> 16));
  }
  if (e < e1) {
    int s0 = csr[e];
    uint2 a = *(const uint2*)(H + (size_t)s0 * 256 + lane * 4);
    acc[0] += bf2f((unsigned short)(a.x & 0xFFFF));
    acc[1] += bf2f((unsigned short)(a.x >> 16));
    acc[2] += bf2f((unsigned short)(a.y & 0xFFFF));
    acc[3] += bf2f((unsigned short)(a.y >> 16));
  }
  unsigned short z[4] = {f2bf(acc[0]), f2bf(acc[1]), f2bf(acc[2]), f2bf(acc[3])};
  *(uint2*)(Z + (size_t)node * 256 + lane * 4) = *(uint2*)z;
}

// ---- GEMM (R16): act(A @ Bt^T + bias), 128x128, BK=64, launch_bounds(256,4) -
// XOR swizzle (0 conflicts) + LDS-staged epilogue + XCD block swizzle +
// reg cap 128/wave -> 4 blocks/CU (VGPR 64, occupancy 32%, no spill).
// MODE 0: C = bf16(relu). MODE 3: nodedot += sum relu(.)*w2v.
template <int K, int NXL, int MODE>
__global__ __launch_bounds__(256, 4)
void gemm_kernel(const unsigned short* __restrict__ A,
                 const unsigned short* __restrict__ Bt,
                 const float* __restrict__ bias, unsigned short* __restrict__ C,
                 const float* __restrict__ w2v, float* __restrict__ nodedot,
                 int M, int N) {
  const int g = blockIdx.x;
  const int mblk = ((g >> (3 + NXL)) << 3) | (g & 7);
  const int nblk = (g >> 3) & ((1 << NXL) - 1);
  const int m0 = mblk * 128;
  const int n0 = nblk * 128;
  if (m0 >= M) return;

  __shared__ unsigned short smem[2 * 128 * 64];  // 32 KB: As+Bs, reused as C-tile
  unsigned short* As = smem;
  unsigned short* Bs = smem + 128 * 64;
  const int tid = threadIdx.x;
  const int lane = tid & 63;
  const int wave = tid >> 6;
  const int wm = (wave & 1) * 64;
  const int wn = (wave >> 1) * 64;
  const int fr = lane & 15;
  const int fq = lane >> 4;

  floatx4 acc[4][4];
#pragma unroll
  for (int i = 0; i < 4; i++)
#pragma unroll
    for (int j = 0; j < 4; j++) acc[i][j] = (floatx4){0.f, 0.f, 0.f, 0.f};

  const unsigned short* gA[4];
  const unsigned short* gB[4];
  unsigned short* lA[4];
  unsigned short* lB[4];
#pragma unroll
  for (int p = 0; p < 4; p++) {
    int c = p * 256 + wave * 64 + lane;
    int row = c >> 3;
    int q = (c & 7) ^ (row & 7);
    int grA = m0 + row;
    if (grA >= M) grA = M - 1;
    gA[p] = A + (size_t)grA * K + q * 8;
    gB[p] = Bt + (size_t)(n0 + row) * K + q * 8;
    lA[p] = &As[(p * 256 + wave * 64) * 8];
    lB[p] = &Bs[(p * 256 + wave * 64) * 8];
  }

  for (int k0 = 0; k0 < K; k0 += 64) {
#pragma unroll
    for (int p = 0; p < 4; p++) cp16(gA[p] + k0, lA[p]);
#pragma unroll
    for (int p = 0; p < 4; p++) cp16(gB[p] + k0, lB[p]);
    __syncthreads();
#pragma unroll
    for (int s0 = 0; s0 < 2; s0++) {
      shortx8 af[4], bf[4];
#pragma unroll
      for (int i = 0; i < 4; i++)
        af[i] = *(const shortx8*)&As[(wm + i * 16 + fr) * 64 +
                                     (((s0 * 4 + fq) ^ (fr & 7)) * 8)];
#pragma unroll
      for (int j = 0; j < 4; j++)
        bf[j] = *(const shortx8*)&Bs[(wn + j * 16 + fr) * 64 +
                                     (((s0 * 4 + fq) ^ (fr & 7)) * 8)];
#pragma unroll
      for (int i = 0; i < 4; i++)
#pragma unroll
        for (int j = 0; j < 4; j++)
          acc[i][j] = __builtin_amdgcn_mfma_f32_16x16x32_bf16(af[i], bf[j], acc[i][j], 0, 0, 0);
    }
    __syncthreads();
  }

  if (MODE == 3) {
    float wv[4], bj[4];
#pragma unroll
    for (int j = 0; j < 4; j++) {
      int col = n0 + wn + j * 16 + fr;
      wv[j] = w2v[col];
      bj[j] = bias[col];
    }
#pragma unroll
    for (int i = 0; i < 4; i++) {
#pragma unroll
      for (int r = 0; r < 4; r++) {
        float p = 0.f;
#pragma unroll
        for (int j = 0; j < 4; j++) p += fmaxf(acc[i][j][r] + bj[j], 0.f) * wv[j];
#pragma unroll
        for (int off = 1; off < 16; off <<= 1) p += __shfl_xor(p, off);
        if (fr == 0) {
          int row = m0 + wm + i * 16 + fq * 4 + r;
          if (row < M) unsafeAtomicAdd(&nodedot[row], p);
        }
      }
    }
  } else {
    unsigned short* Cs = smem;
#pragma unroll
    for (int j = 0; j < 4; j++) {
      int col = wn + j * 16 + fr;
      float bj = bias[n0 + col];
#pragma unroll
      for (int i = 0; i < 4; i++) {
#pragma unroll
        for (int r = 0; r < 4; r++) {
          int row = wm + i * 16 + fq * 4 + r;
          Cs[row * 128 + col] = f2bf(fmaxf(acc[i][j][r] + bj, 0.f));
        }
      }
    }
    __syncthreads();
    const int rcol = (tid & 15) * 8;
#pragma unroll
    for (int p = 0; p < 8; p++) {
      int row = p * 16 + (tid >> 4);
      int grow = m0 + row;
      if (grow < M) {
        uint4 v = *(const uint4*)&Cs[row * 128 + rcol];
        *(uint4*)&C[(size_t)grow * N + n0 + rcol] = v;
      }
    }
  }
}

// ---------------- readout ----------------------------------------------------
__global__ __launch_bounds__(256)
void pool_kernel(const float* __restrict__ nodedot, const int* __restrict__ batch,
                 float* __restrict__ out, const float* __restrict__ c2p) {
  int t = blockIdx.x * 256 + threadIdx.x;
  int i0 = t * 64;
  if (i0 >= N_NODES) return;
  int i1 = i0 + 64;
  if (i1 > N_NODES) i1 = N_NODES;
  const float c2 = *c2p;
  int g = batch[i0];
  float s = 0.f;
  for (int i = i0; i < i1; i++) {
    int gi = batch[i];
    if (gi != g) { unsafeAtomicAdd(&out[g], s); g = gi; s = 0.f; }
    s += nodedot[i] + c2;
  }
  unsafeAtomicAdd(&out[g], s);
}

extern "C" void kernel_launch(void* const* d_in, const int* in_sizes, int n_in,
                              void* d_out, int out_size, void* d_ws, size_t ws_size,
                              hipStream_t stream) {
  const float* x       = (const float*)d_in[0];
  const int*   ei      = (const int*)d_in[1];
  const int*   batch   = (const int*)d_in[2];
  const float* W_embed = (const float*)d_in[3];
  const float* b_embed = (const float*)d_in[4];
  const float* eps     = (const float*)d_in[5];
  const float* W1[3] = {(const float*)d_in[6],  (const float*)d_in[10], (const float*)d_in[14]};
  const float* B1[3] = {(const float*)d_in[7],  (const float*)d_in[11], (const float*)d_in[15]};
  const float* W2[3] = {(const float*)d_in[8],  (const float*)d_in[12], (const float*)d_in[16]};
  const float* B2[3] = {(const float*)d_in[9],  (const float*)d_in[13], (const float*)d_in[17]};
  const float* W_task = (const float*)d_in[18];
  const float* b_task = (const float*)d_in[19];
  float* out = (float*)d_out;

  const size_t OFF_RB  = 51200000;
  const size_t OFF_RZ  = 102400000;
  const size_t OFF_AUX = 153600000;
  if (ws_size < OFF_AUX + 4000000) return;
  unsigned short* RH = (unsigned short*)d_ws;
  unsigned short* RB = (unsigned short*)((char*)d_ws + OFF_RB);
  unsigned short* RZ = (unsigned short*)((char*)d_ws + OFF_RZ);
  char* aux = (char*)d_ws + OFF_AUX;
  int* row_ptr  = (int*)(aux);               // 100001 ints
  int* cursor   = (int*)(aux + 400016);      // 100000 ints (also deg histogram)
  int* csr_src  = (int*)(aux + 800016);      // 300000 ints
  int* blk_sums = (int*)(aux + 2000016);     // 98 ints
  int* blk_off  = (int*)(aux + 2000416);     // 98 ints
  float* nodedot = (float*)(aux + 2000816);  // 100000 floats
  unsigned short* WT = (unsigned short*)(aux + 2400832);  // 360448 bf16
  float* w2v = (float*)(aux + 3200832);      // 512 floats
  float* c2  = (float*)(aux + 3202880);      // 1 float
  unsigned short* WfT    = WT;
  unsigned short* Wt2_0  = WT + 32768;
  unsigned short* Wt1_1  = WT + 98304;
  unsigned short* Wt2_1  = WT + 163840;
  unsigned short* Wt1_2  = WT + 229376;

  // ---- prep: all independent prologue work (1 dispatch) ----
  PrepArgs pa;
  pa.W[0] = W2[0]; pa.Wt[0] = Wt2_0; pa.K[0] = 256; pa.N[0] = 256;
  pa.W[1] = W1[1]; pa.Wt[1] = Wt1_1; pa.K[1] = 256; pa.N[1] = 256;
  pa.W[2] = W2[1]; pa.Wt[2] = Wt2_1; pa.K[2] = 256; pa.N[2] = 256;
  pa.W[3] = W1[2]; pa.Wt[3] = Wt1_2; pa.K[3] = 256; pa.N[3] = 512;
  pa.We = W_embed; pa.be = b_embed; pa.W1_0 = W1[0]; pa.WfT = WfT;
  pa.W2_2 = W2[2]; pa.b2_2 = B2[2]; pa.wtask = W_task; pa.w2v = w2v; pa.c2 = c2;
  pa.nodedot = nodedot; pa.out = out; pa.b_task = b_task;
  prep_kernel<<<889, 256, 0, stream>>>(pa);

  // ---- CSR build ----
  zero_kernel<<<(N_NODES + 255) / 256, 256, 0, stream>>>(cursor, N_NODES);
  hist_kernel<<<(E_EDGES + 255) / 256, 256, 0, stream>>>(ei, cursor);
  scan_blk_kernel<<<98, 256, 0, stream>>>(cursor, row_ptr, blk_sums, N_NODES, N_NODES + 1);
  scan_blk_kernel<<<1, 256, 0, stream>>>(blk_sums, blk_off, nullptr, 98, 98);
  scan_fix_kernel<<<(N_NODES + 256) / 256, 256, 0, stream>>>(row_ptr, blk_off, cursor);
  fill_kernel<<<(E_EDGES + 255) / 256, 256, 0, stream>>>(ei, cursor, csr_src);

  const int MB = (N_NODES + 127) / 128;       // 782
  const int MB8 = ((MB + 7) / 8) * 8;         // 784 (padded; tail blocks exit)

  // ---- layer 0 (folded): G = gather(X)+deg-slot -> T0 = relu(G@WfT^T + b1) --
  gatherx_kernel<<<N_NODES / 4, 256, 0, stream>>>(x, RZ, row_ptr, csr_src, eps);
  gemm_kernel<64, 1, 0><<<2 * MB8, 256, 0, stream>>>(RZ, WfT, B1[0], RB, nullptr, nullptr, N_NODES, 256);
  gemm_kernel<256, 1, 0><<<2 * MB8, 256, 0, stream>>>(RB, Wt2_0, B2[0], RH, nullptr, nullptr, N_NODES, 256);

  // ---- layer 1 ----
  gather_kernel<<<N_NODES / 4, 256, 0, stream>>>(RH, RZ, row_ptr, csr_src, eps, 1);
  gemm_kernel<256, 1, 0><<<2 * MB8, 256, 0, stream>>>(RZ, Wt1_1, B1[1], RB, nullptr, nullptr, N_NODES, 256);
  gemm_kernel<256, 1, 0><<<2 * MB8, 256, 0, stream>>>(RB, Wt2_1, B2[1], RH, nullptr, nullptr, N_NODES, 256);

  // ---- layer 2: gather, then MODE-3 GEMM (task-dot fused) ----
  gather_kernel<<<N_NODES / 4, 256, 0, stream>>>(RH, RZ, row_ptr, csr_src, eps, 2);
  gemm_kernel<256, 2, 3><<<4 * MB8, 256, 0, stream>>>(RZ, Wt1_2, B1[2], nullptr, w2v, nodedot, N_NODES, 512);

  // ---- out[g] = b_task + sum_i (nodedot_i + c2) ----
  pool_kernel<<<((N_NODES + 63) / 64 + 255) / 256, 256, 0, stream>>>(nodedot, batch, out, c2);
}